// Round 11
// baseline (299.356 us; speedup 1.0000x reference)
//
#include <hip/hip_runtime.h>
#include <hip/hip_bf16.h>
#include <math.h>

typedef __attribute__((ext_vector_type(8))) short short8;
typedef __attribute__((ext_vector_type(4))) float f32x4;

#define NT 8   // n-values pipelined per big block

// ---------------------------------------------------------------------------
// prep (fused pack+proj):
//  blocks [0,128):  rx = x@lambda_x + b, xp = x@theta1   (dual accumulate)
//  blocks [128,256): ry = y@lambda_y + b
//  blocks [256,384): Wh/Wl[o'][q] bf16 hi/lo (o' = h*32+which*16+d),
//                    T2[o][q] = theta2[h][q][d], ob[q] = sum bth*theta2
// ---------------------------------------------------------------------------
__global__ __launch_bounds__(128) void prep_kernel(
        const float* __restrict__ x,  const float* __restrict__ y,
        const float* __restrict__ lx, const float* __restrict__ ly,
        const float* __restrict__ t1,
        const float* __restrict__ lz1, const float* __restrict__ lz2,
        const float* __restrict__ th2, const float* __restrict__ bth,
        const float* __restrict__ blx, const float* __restrict__ bly,
        __hip_bfloat16* __restrict__ Wh, __hip_bfloat16* __restrict__ Wl,
        float* __restrict__ T2, float* __restrict__ ob,
        float* __restrict__ rx, float* __restrict__ ry, float* __restrict__ xp) {
    const int bid = blockIdx.x;
    const int t = threadIdx.x;
    if (bid < 256) {
        __shared__ float rows[4][128];
        const int role = bid >> 7;              // 0: x, 1: y
        const int n0 = (bid & 127) * 4;
        const float* in = role ? y : x;
        const int o = t, h = o >> 4, d = o & 15;
#pragma unroll
        for (int j = 0; j < 4; ++j)
            rows[j][o] = in[(n0 + j) * 128 + o];
        __syncthreads();
        if (role == 0) {
            float a[4] = {0.f, 0.f, 0.f, 0.f}, b[4] = {0.f, 0.f, 0.f, 0.f};
#pragma unroll 4
            for (int q = 0; q < 128; ++q) {
                float wa = lx[(h * 128 + q) * 16 + d];
                float wb = t1[(h * 128 + q) * 16 + d];
#pragma unroll
                for (int j = 0; j < 4; ++j) {
                    a[j] = fmaf(rows[j][q], wa, a[j]);
                    b[j] = fmaf(rows[j][q], wb, b[j]);
                }
            }
            float bx = blx[o];
#pragma unroll
            for (int j = 0; j < 4; ++j) {
                rx[(n0 + j) * 128 + o] = a[j] + bx;
                xp[(n0 + j) * 128 + o] = b[j];
            }
        } else {
            float a[4] = {0.f, 0.f, 0.f, 0.f};
#pragma unroll 4
            for (int q = 0; q < 128; ++q) {
                float wa = ly[(h * 128 + q) * 16 + d];
#pragma unroll
                for (int j = 0; j < 4; ++j)
                    a[j] = fmaf(rows[j][q], wa, a[j]);
            }
            float by = bly[o];
#pragma unroll
            for (int j = 0; j < 4; ++j)
                ry[(n0 + j) * 128 + o] = a[j] + by;
        }
    } else {
        const int idx = (bid - 256) * 128 + t;  // 0..16383
#pragma unroll
        for (int i = idx; i < 32768; i += 16384) {
            int op = i >> 7, q = i & 127;
            int h = op >> 5, wh = (op >> 4) & 1, d = op & 15;
            float v = (wh ? lz2 : lz1)[(h * 128 + q) * 16 + d];
            __hip_bfloat16 hb = __float2bfloat16(v);
            Wh[i] = hb;
            Wl[i] = __float2bfloat16(v - __bfloat162float(hb));
        }
        {
            int o = idx >> 7, q = idx & 127;
            int h = o >> 4, d = o & 15;
            T2[idx] = th2[(h * 128 + q) * 16 + d];
        }
        if (idx < 128) {
            int q = idx;
            float s = 0.f;
#pragma unroll
            for (int h = 0; h < 8; ++h)
#pragma unroll
                for (int c = 0; c < 4; ++c) {
                    float4 a = *(const float4*)&bth[h * 16 + c * 4];
                    float4 b = *(const float4*)&th2[(h * 128 + q) * 16 + c * 4];
                    s += a.x * b.x + a.y * b.y + a.z * b.z + a.w * b.w;
                }
            ob[q] = s;
        }
    }
}

// ---------------------------------------------------------------------------
// big v5: block = (64-m tile, 8 n), 4 waves. SINGLE-buffer 32 KB LDS
// (R9: 64 KB dbuf -> 1 block/CU, Occupancy 10%, no inter-block overlap;
// now ~5 blocks/CU co-resident cover the two barriers per t).
// Loads for t+1 in regs while computing t; convert+write after barrier.
// Writes w = exp(att-10) (unnormalized softmax numerator; masked -> 0).
// ---------------------------------------------------------------------------
__global__ __launch_bounds__(256) void big_kernel(
        const float* __restrict__ z,
        const int* __restrict__ mask,
        const __hip_bfloat16* __restrict__ Wh,
        const __hip_bfloat16* __restrict__ Wl,
        const float* __restrict__ rx,
        const float* __restrict__ ry,
        float* __restrict__ w) {
    __shared__ short zsh[64 * 128];   // 16 KB hi
    __shared__ short zsl[64 * 128];   // 16 KB lo
    const int m0 = blockIdx.x * 64;
    const int n0 = blockIdx.y * NT;
    const int tid = threadIdx.x;
    const int og = tid >> 6;
    const int l  = tid & 63;
    const int lg = l >> 4;
    const int lm = l & 15;

    const int srow = tid >> 2, kseg = tid & 3;
    const float* zbase = &z[(size_t)(m0 + srow) * 128 + kseg * 32];

    // ry depends only on m: hoist (32 VGPR)
    float4 ryr[2][4];
#pragma unroll
    for (int p = 0; p < 2; ++p)
#pragma unroll
        for (int i = 0; i < 4; ++i)
            ryr[p][i] = *(const float4*)&ry[(size_t)(m0 + i * 16 + lm) * 128 + (og * 2 + p) * 16 + lg * 4];

    float4 zr[8];
#define LOADZ(nn)                                                         \
    {                                                                     \
        const float* p_ = zbase + (size_t)(nn) * 65536;                   \
        _Pragma("unroll")                                                 \
        for (int c_ = 0; c_ < 8; ++c_) zr[c_] = *(const float4*)&p_[c_ * 4]; \
    }

#define CONVERT_WRITE()                                                   \
    {                                                                     \
        _Pragma("unroll")                                                 \
        for (int c8 = 0; c8 < 4; ++c8) {                                  \
            float vv[8] = {zr[2 * c8].x, zr[2 * c8].y, zr[2 * c8].z, zr[2 * c8].w, \
                           zr[2 * c8 + 1].x, zr[2 * c8 + 1].y, zr[2 * c8 + 1].z, zr[2 * c8 + 1].w}; \
            union { short8 s; __hip_bfloat16 h[8]; } uh, ul;              \
            _Pragma("unroll")                                             \
            for (int jj = 0; jj < 8; ++jj) {                              \
                float f_ = vv[jj];                                        \
                __hip_bfloat16 hb_ = __float2bfloat16(f_);                \
                uh.h[jj] = hb_;                                           \
                ul.h[jj] = __float2bfloat16(f_ - __bfloat162float(hb_));  \
            }                                                             \
            int cw_ = (kseg * 4 + c8) ^ (srow & 7);                       \
            *(short8*)&zsh[srow * 128 + cw_ * 8] = uh.s;                  \
            *(short8*)&zsl[srow * 128 + cw_ * 8] = ul.s;                  \
        }                                                                 \
    }

    LOADZ(n0);
    CONVERT_WRITE();
    LOADZ(n0 + 1);
    __syncthreads();

    for (int t = 0; t < NT; ++t) {
        const int n = n0 + t;
        const int mk = mask[n * 512 + m0 + l];

        f32x4 acc[4][4];    // [edge-tile i][pj = p*2+j]
#pragma unroll
        for (int i = 0; i < 4; ++i)
#pragma unroll
            for (int pj = 0; pj < 4; ++pj) acc[i][pj] = (f32x4){0.f, 0.f, 0.f, 0.f};

#pragma unroll
        for (int ks = 0; ks < 4; ++ks) {
            short8 ah[4], al[4];
#pragma unroll
            for (int i = 0; i < 4; ++i) {
                int row = i * 16 + lm;
                int cw = (ks * 4 + lg) ^ (row & 7);
                ah[i] = *(const short8*)&zsh[row * 128 + cw * 8];
                al[i] = *(const short8*)&zsl[row * 128 + cw * 8];
            }
#pragma unroll
            for (int pj = 0; pj < 4; ++pj) {
                size_t off = (size_t)(og * 64 + pj * 16 + lm) * 128 + ks * 32 + lg * 8;
                short8 bh = *(const short8*)&Wh[off];
                short8 bl = *(const short8*)&Wl[off];
#pragma unroll
                for (int i = 0; i < 4; ++i) {
                    acc[i][pj] = __builtin_amdgcn_mfma_f32_16x16x32_bf16(bh, ah[i], acc[i][pj], 0, 0, 0);
                    acc[i][pj] = __builtin_amdgcn_mfma_f32_16x16x32_bf16(bh, al[i], acc[i][pj], 0, 0, 0);
                    acc[i][pj] = __builtin_amdgcn_mfma_f32_16x16x32_bf16(bl, ah[i], acc[i][pj], 0, 0, 0);
                }
            }
        }
        __syncthreads();                 // all waves done reading LDS tile t

        if (t + 1 < NT) {
            CONVERT_WRITE();             // stage tile t+1
            if (t + 2 < NT) LOADZ(n0 + t + 2);
        }

        // epilogue (register-only): d-sum over r, 2 shfl over lg strata
#pragma unroll
        for (int p = 0; p < 2; ++p) {
            const int h = og * 2 + p;
            float4 rxt = *(const float4*)&rx[n * 128 + h * 16 + lg * 4];
            const float rxv[4] = {rxt.x, rxt.y, rxt.z, rxt.w};
            float t4[4];
#pragma unroll
            for (int i = 0; i < 4; ++i) {
                const float ryv[4] = {ryr[p][i].x, ryr[p][i].y, ryr[p][i].z, ryr[p][i].w};
                float s = 0.f;
#pragma unroll
                for (int r = 0; r < 4; ++r)
                    s = fmaf(rxv[r] + acc[i][p * 2][r], ryv[r] + acc[i][p * 2 + 1][r], s);
                s += __shfl_xor(s, 16);
                s += __shfl_xor(s, 32);
                t4[i] = s;
            }
            float ta = (lg & 1) ? t4[1] : t4[0];
            float tb = (lg & 1) ? t4[3] : t4[2];
            float s  = (lg & 2) ? tb : ta;
            // w = exp(10*tanh(0.25 s) - 10) = exp(-20/(exp(0.5 s)+1))
            float e1 = __expf(0.5f * s);
            float wv = __expf(-20.f / (e1 + 1.f));
            if (mk == 1) wv = 0.f;
            w[((size_t)(h * 512 + n)) * 512 + m0 + l] = wv;
        }

        if (t + 1 < NT) __syncthreads(); // tile t+1 visible to all waves
    }
#undef LOADZ
#undef CONVERT_WRITE
}

// ---------------------------------------------------------------------------
// pv: softmax-denominator + PV, no xp LDS (direct L2 reads; per-wave traffic
// equals staging but zero bank conflicts, zero phase barriers).
// Block = (8-m tile, h), grid 64x8 = 512 blocks. 256 thr = 8 m x 32 n-strips.
// rr[m][h*16+d] = sum_n w[h][n][m]*xp[n][h*16+d] / sum_n w[h][n][m]
// ---------------------------------------------------------------------------
__global__ __launch_bounds__(256) void pv_kernel(
        const float* __restrict__ w,
        const float* __restrict__ xp,
        float* __restrict__ rr) {
    __shared__ float red[32][8][17];    // pad 17: avoid 8-way write conflicts
    __shared__ float ssum[32][9];
    const int m0 = blockIdx.x * 8;
    const int h  = blockIdx.y;
    const int t  = threadIdx.x;
    const int ml = t & 7, g = t >> 3;

    const float* wcol = &w[(size_t)h * 262144 + m0 + ml];
    const float* xph  = &xp[h * 16];

    float racc[16];
#pragma unroll
    for (int dd = 0; dd < 16; ++dd) racc[dd] = 0.f;
    float s = 0.f;
    const int nnb = g * 16;
#pragma unroll
    for (int i = 0; i < 16; ++i) {
        const int nn = nnb + i;
        float e = wcol[(size_t)nn * 512];
        s += e;
        const float4* xr = (const float4*)&xph[nn * 128];
        float4 x0 = xr[0], x1 = xr[1], x2 = xr[2], x3 = xr[3];
        racc[0]  = fmaf(e, x0.x, racc[0]);  racc[1]  = fmaf(e, x0.y, racc[1]);
        racc[2]  = fmaf(e, x0.z, racc[2]);  racc[3]  = fmaf(e, x0.w, racc[3]);
        racc[4]  = fmaf(e, x1.x, racc[4]);  racc[5]  = fmaf(e, x1.y, racc[5]);
        racc[6]  = fmaf(e, x1.z, racc[6]);  racc[7]  = fmaf(e, x1.w, racc[7]);
        racc[8]  = fmaf(e, x2.x, racc[8]);  racc[9]  = fmaf(e, x2.y, racc[9]);
        racc[10] = fmaf(e, x2.z, racc[10]); racc[11] = fmaf(e, x2.w, racc[11]);
        racc[12] = fmaf(e, x3.x, racc[12]); racc[13] = fmaf(e, x3.y, racc[13]);
        racc[14] = fmaf(e, x3.z, racc[14]); racc[15] = fmaf(e, x3.w, racc[15]);
    }
    ssum[g][ml] = s;
#pragma unroll
    for (int dd = 0; dd < 16; ++dd) red[g][ml][dd] = racc[dd];
    __syncthreads();

    if (t < 128) {
        const int m = t & 7, dd = t >> 3;
        float stot = 0.f;
#pragma unroll
        for (int gg = 0; gg < 32; ++gg) stot += ssum[gg][m];
        float v = 0.f;
#pragma unroll
        for (int gg = 0; gg < 32; ++gg) v += red[gg][m][dd];
        rr[(size_t)(m0 + m) * 128 + h * 16 + dd] = v / stot;
    }
}

// ---------------------------------------------------------------------------
// outg: block = 4 m rows, 128 thr (q). out[m][q] = ob[q] + sum_o rr[m][o]*T2[o][q]
// ---------------------------------------------------------------------------
__global__ __launch_bounds__(128) void outg_kernel(const float* __restrict__ rr,
                            const float* __restrict__ T2,
                            const float* __restrict__ ob,
                            float* __restrict__ out) {
    __shared__ float rrow[4][128];
    const int m0 = blockIdx.x * 4;
    const int q = threadIdx.x;
#pragma unroll
    for (int j = 0; j < 4; ++j)
        rrow[j][q] = rr[(m0 + j) * 128 + q];
    __syncthreads();
    float acc[4] = {0.f, 0.f, 0.f, 0.f};
#pragma unroll 4
    for (int o = 0; o < 128; ++o) {
        float tv = T2[o * 128 + q];
#pragma unroll
        for (int j = 0; j < 4; ++j)
            acc[j] = fmaf(rrow[j][o], tv, acc[j]);
    }
    float b = ob[q];
#pragma unroll
    for (int j = 0; j < 4; ++j)
        out[(m0 + j) * 128 + q] = acc[j] + b;
}

extern "C" void kernel_launch(void* const* d_in, const int* in_sizes, int n_in,
                              void* d_out, int out_size, void* d_ws, size_t ws_size,
                              hipStream_t stream) {
    (void)in_sizes; (void)n_in; (void)out_size; (void)ws_size;
    const float* x   = (const float*)d_in[0];
    const float* y   = (const float*)d_in[1];
    const float* z   = (const float*)d_in[2];
    const int*  mask = (const int*)d_in[3];
    const float* lx  = (const float*)d_in[4];
    const float* ly  = (const float*)d_in[5];
    const float* lz1 = (const float*)d_in[6];
    const float* lz2 = (const float*)d_in[7];
    const float* blx = (const float*)d_in[8];
    const float* bly = (const float*)d_in[9];
    const float* t1  = (const float*)d_in[10];
    const float* t2  = (const float*)d_in[11];
    const float* bth = (const float*)d_in[12];
    float* out = (float*)d_out;

    float* ws = (float*)d_ws;
    float* rx = ws;                               // 65536
    float* ry = rx + 65536;                       // 65536
    float* xp = ry + 65536;                       // 65536
    __hip_bfloat16* Wh = (__hip_bfloat16*)(xp + 65536);         // 32768 bf16
    __hip_bfloat16* Wl = (__hip_bfloat16*)(xp + 65536 + 16384); // 32768 bf16
    float* T2  = xp + 65536 + 32768;              // 16384
    float* ob  = T2 + 16384;                      // 128
    float* wbuf= ob + 128;                        // 8*512*512 = 2097152
    float* rr  = wbuf + 2097152;                  // 65536

    prep_kernel<<<dim3(384), dim3(128), 0, stream>>>(
        x, y, lx, ly, t1, lz1, lz2, t2, bth, blx, bly,
        Wh, Wl, T2, ob, rx, ry, xp);
    big_kernel<<<dim3(8, 64), dim3(256), 0, stream>>>(z, mask, Wh, Wl, rx, ry, wbuf);
    pv_kernel<<<dim3(64, 8), dim3(256), 0, stream>>>(wbuf, xp, rr);
    outg_kernel<<<dim3(128), dim3(128), 0, stream>>>(rr, T2, ob, out);
}